// Round 1
// baseline (201.948 us; speedup 1.0000x reference)
//
#include <hip/hip_runtime.h>

// LocalizationVAE spot rendering:
//   B=8192 images of 64x64, 64 Gaussian-integrated spots each.
//   Memory-bound: 128 MiB out write + 4 MiB in read -> ~21us roofline @6.3TB/s.
// Strategy: one 256-thread block per batch image. Accumulate image in 16 KiB
// LDS via ds_add_f32 atomics (avoids global zeroing + global RMW), write out
// coalesced float4.

constexpr int NXc = 64;
constexpr int NYc = 64;
constexpr int PATCH_HW = 3;
constexpr int PP = 6;                      // patch side = 2*PATCH_HW
constexpr float I0c = 1000.0f;
// 1 / (sqrt(2) * 0.92)
constexpr float INV_ALPHA = 0.76859415f;

__global__ __launch_bounds__(256) void loc_spots_kernel(
        const float* __restrict__ z, float* __restrict__ out) {
    __shared__ float mu[NXc * NYc];        // 16 KiB
    const int b   = blockIdx.x;
    const int tid = threadIdx.x;

    // zero the LDS image (1024 float4 / 256 threads = 4 iters)
    float4* mu4 = reinterpret_cast<float4*>(mu);
#pragma unroll
    for (int i = 0; i < 4; ++i)
        mu4[tid + i * 256] = make_float4(0.f, 0.f, 0.f, 0.f);
    __syncthreads();

    const int s = tid & 63;                // spot index
    const int g = tid >> 6;                // pixel group 0..3 (9 pixels each)

    // z row layout: [x0[0..63], y0[0..63]]
    const float x0 = z[b * 128 + s];
    const float y0 = z[b * 128 + 64 + s];

    // jnp.round = half-to-even = rintf
    const int px = (int)rintf(x0) - PATCH_HW;
    const int py = (int)rintf(y0) - PATCH_HW;
    const bool valid = (px >= 0) && (px < NXc - PP) && (py >= 0) && (py < NYc - PP);

    if (valid) {
        const float x0p = x0 - (float)px;
        const float y0p = y0 - (float)py;

        // erf boundary values at t-0.5 for t=0..6; lam[t]=0.5*(b[t+1]-b[t])
        float bx[PP + 1], by[PP + 1];
#pragma unroll
        for (int k = 0; k <= PP; ++k) {
            bx[k] = erff(((float)k - 0.5f - x0p) * INV_ALPHA);
            by[k] = erff(((float)k - 0.5f - y0p) * INV_ALPHA);
        }
        float lx[PP], ly[PP];
#pragma unroll
        for (int t = 0; t < PP; ++t) {
            lx[t] = 0.5f * (bx[t + 1] - bx[t]);
            ly[t] = 0.5f * (by[t + 1] - by[t]);
        }

        // this thread handles 9 of the 36 patch pixels
        const int base = px * NYc + py;
#pragma unroll
        for (int q = 0; q < 9; ++q) {
            const int p = g * 9 + q;
            const int i = p / 6;
            const int j = p - i * 6;
            atomicAdd(&mu[base + i * NYc + j], I0c * lx[i] * ly[j]);
        }
    }
    __syncthreads();

    // coalesced writeout: 1024 float4 / 256 threads = 4 iters
    float4* out4 = reinterpret_cast<float4*>(out + (size_t)b * (NXc * NYc));
#pragma unroll
    for (int i = 0; i < 4; ++i)
        out4[tid + i * 256] = mu4[tid + i * 256];
}

extern "C" void kernel_launch(void* const* d_in, const int* in_sizes, int n_in,
                              void* d_out, int out_size, void* d_ws, size_t ws_size,
                              hipStream_t stream) {
    const float* z = (const float*)d_in[0];
    float* out = (float*)d_out;
    const int B = in_sizes[0] / 128;       // 8192
    loc_spots_kernel<<<B, 256, 0, stream>>>(z, out);
}

// Round 2
// 196.076 us; speedup vs baseline: 1.0299x; 1.0299x over previous
//
#include <hip/hip_runtime.h>

// LocalizationVAE spot rendering: B=8192 images 64x64, 64 spots each.
// R1 -> R2: one wave per image (64-thread block), one thread per spot.
//   - kills the 4x redundant erf of the 4-pixel-group layout
//   - fast A&S erf (rcp + exp, ~14 inst, |eps|<=1.5e-7) instead of ocml erff
//   - private 16 KiB LDS image per wave, ds atomics, coalesced float4 out
// Expected limiter: 131 MiB HBM write stream.

constexpr int NXc = 64;
constexpr int NYc = 64;
constexpr int IMG = NXc * NYc;             // 4096 floats = 16 KiB
constexpr int PATCH_HW = 3;
constexpr int PP = 6;
constexpr float I0c = 1000.0f;
constexpr float INV_ALPHA = 0.76859415f;   // 1/(sqrt(2)*0.92)

// Abramowitz & Stegun 7.1.26, |error| <= 1.5e-7 over all x
__device__ __forceinline__ float fast_erf(float x) {
    const float ax = __builtin_fabsf(x);
    const float t  = __builtin_amdgcn_rcpf(__builtin_fmaf(0.3275911f, ax, 1.0f));
    float y = __builtin_fmaf(1.061405429f, t, -1.453152027f);
    y = __builtin_fmaf(y, t, 1.421413741f);
    y = __builtin_fmaf(y, t, -0.284496736f);
    y = __builtin_fmaf(y, t, 0.254829592f);
    y = y * t;
    const float e = __expf(-ax * ax);
    const float r = __builtin_fmaf(-y, e, 1.0f);
    return __builtin_copysignf(r, x);
}

__global__ __launch_bounds__(64) void loc_spots_kernel(
        const float* __restrict__ z, float* __restrict__ out) {
    __shared__ float mu[IMG];              // 16 KiB, private to this wave
    const int b = blockIdx.x;
    const int l = threadIdx.x;             // lane == spot index

    // issue spot loads early (cold HBM latency overlaps the LDS zeroing)
    const float x0 = z[b * 128 + l];
    const float y0 = z[b * 128 + 64 + l];

    // zero LDS image: 16 x ds_write_b128 per lane
    float4* mu4 = reinterpret_cast<float4*>(mu);
#pragma unroll
    for (int i = 0; i < 16; ++i)
        mu4[l + i * 64] = make_float4(0.f, 0.f, 0.f, 0.f);
    __syncthreads();

    // jnp.round = half-to-even = rintf
    const int px = (int)rintf(x0) - PATCH_HW;
    const int py = (int)rintf(y0) - PATCH_HW;
    const bool valid = (px >= 0) && (px < NXc - PP) && (py >= 0) && (py < NYc - PP);

    if (valid) {
        const float x0p = x0 - (float)px;
        const float y0p = y0 - (float)py;

        float bx[PP + 1], by[PP + 1];
#pragma unroll
        for (int k = 0; k <= PP; ++k) {
            bx[k] = fast_erf(((float)k - 0.5f - x0p) * INV_ALPHA);
            by[k] = fast_erf(((float)k - 0.5f - y0p) * INV_ALPHA);
        }
        float lxs[PP], ly[PP];
#pragma unroll
        for (int t = 0; t < PP; ++t) {
            lxs[t] = (0.5f * I0c) * (bx[t + 1] - bx[t]);   // premultiply I0
            ly[t]  = 0.5f * (by[t + 1] - by[t]);
        }

        const int base = px * NYc + py;
#pragma unroll
        for (int i = 0; i < PP; ++i)
#pragma unroll
            for (int j = 0; j < PP; ++j)
                atomicAdd(&mu[base + i * NYc + j], lxs[i] * ly[j]);
    }
    __syncthreads();

    // coalesced writeout: 16 x (ds_read_b128 + global_store_dwordx4) per lane
    float4* out4 = reinterpret_cast<float4*>(out + (size_t)b * IMG);
#pragma unroll
    for (int i = 0; i < 16; ++i)
        out4[l + i * 64] = mu4[l + i * 64];
}

extern "C" void kernel_launch(void* const* d_in, const int* in_sizes, int n_in,
                              void* d_out, int out_size, void* d_ws, size_t ws_size,
                              hipStream_t stream) {
    const float* z = (const float*)d_in[0];
    float* out = (float*)d_out;
    const int B = in_sizes[0] / 128;       // 8192 images
    loc_spots_kernel<<<B, 64, 0, stream>>>(z, out);
}